// Round 14
// baseline (41.214 us; speedup 1.0000x reference)
//
#include <hip/hip_runtime.h>
#include <hip/hip_bf16.h>
#include <math.h>

// out[n] = top1(s) - top2(s),  s_c = 2 mu_c.x - ||mu_c||^2
//
// Kernel 1 (96 blocks x 64 thr): compact bf16 B-fragment table (64 KB) in
//   PER-WAVE GATHER ORDER + bf16-consistent ||mu||^2 (128 B) into d_ws.
//   Main-kernel prologue then reads 8 KB LINEAR per wave (L2-friendly)
//   instead of 16 KB of 4KB-strided fp32 -- halves the per-block re-fetch
//   traffic that was stealing HBM BW (511 blocks x gather).
// Kernel 2 (511 blocks x 512 thr, 98 rows/block, 2 blocks/CU): K-split:
//   wave w owns dims [128w,128w+128); B-frags in 32 VGPR/lane from tbl;
//   X streamed with NONTEMPORAL loads (zero reuse -> don't evict tbl/L2)
//   as 512B row-pair bursts into wave-private 4KB XOR-swizzled LDS; 4
//   k-steps {ds_read_b128 + 2 MFMA}; partials -> ldsP[t&1] (row-XOR
//   swizzle); ONE raw barrier/tile (lgkmcnt only -- vmcnt never drained);
//   8-wave reduce + fused top-2. No prologue barrier at all (sq via 3
//   scalar global loads).
// A and B use the same k-slot mapping -> dot invariant to slot permutation.

#define KTOT  32
#define DDIM  1024
#define BLK   512
#define RPB   98
#define TILES 7      // ceil(98/16)

typedef __attribute__((ext_vector_type(8))) short short8v;
typedef __attribute__((ext_vector_type(4))) short short4v;
typedef __attribute__((ext_vector_type(4))) float f32x4;

__device__ __forceinline__ short f2bf(float x) {  // RNE; pairs into v_cvt_pk_bf16_f32
  __hip_bfloat16 h = __float2bfloat16(x);
  return __builtin_bit_cast(short, h);
}
__device__ __forceinline__ float bf2f(short b) {
  return __uint_as_float(((unsigned)(unsigned short)b) << 16);
}

// ---------------- kernel 1: compact frag table (gather order) + sq --------
__global__ __launch_bounds__(64)
void nkm_pre_kernel(const float* __restrict__ Cent, short* __restrict__ tbl) {
  const int b = blockIdx.x, t = threadIdx.x;
  if (b < 64) {
    // item i = ((wid*4+sp)*2+h)*64 + lane  (exactly main-kernel read order)
    const int i    = b * 64 + t;         // 0..4095
    const int lane = i & 63;
    const int sh   = i >> 6;             // (wid*4+sp)*2+h
    const int h    = sh & 1;
    const int sp   = (sh >> 1) & 3;
    const int wid  = sh >> 3;
    const int cc   = lane & 15, g = lane >> 4;
    const int col  = cc + (h << 4);
    const float* cp = Cent + (size_t)col * DDIM + (wid << 7) + sp * 32 + (g << 3);
    f32x4 f0 = *(const f32x4*)cp;
    f32x4 f1 = *(const f32x4*)(cp + 4);
    short8v v;
    v[0] = f2bf(f0[0]); v[1] = f2bf(f0[1]); v[2] = f2bf(f0[2]); v[3] = f2bf(f0[3]);
    v[4] = f2bf(f1[0]); v[5] = f2bf(f1[1]); v[6] = f2bf(f1[2]); v[7] = f2bf(f1[3]);
    *(short8v*)(tbl + (size_t)i * 8) = v;
  } else {
    // ||mu_col||^2 from bf16-ROUNDED values (operand-consistent with MFMA B)
    const int col = b - 64;              // 0..31
    const float* cp = Cent + (size_t)col * DDIM + t * 16;
    float s = 0.f;
    #pragma unroll
    for (int j = 0; j < 4; ++j) {
      f32x4 v = *(const f32x4*)(cp + j * 4);
      #pragma unroll
      for (int e = 0; e < 4; ++e) {
        float bv = bf2f(f2bf(v[e]));
        s = fmaf(bv, bv, s);
      }
    }
    #pragma unroll
    for (int d = 1; d < 64; d <<= 1) s += __shfl_xor(s, d, 64);
    if (t == 0) ((float*)(tbl + 32768))[col] = s;
  }
}

// ---------------- kernel 2: K-split streamer ------------------------------
__global__ __launch_bounds__(BLK, 4)
void nkm_ksplit_kernel(const float* __restrict__ X,
                       const short* __restrict__ tbl,
                       float* __restrict__ out, int N) {
  __shared__ short ldsX[16384];    // 32 KB: 8 waves x 4 KB X-stage (wave-private)
  __shared__ float ldsP[2][4096];  // 2 x 16 KB: [buf][8 waves][16 rows][32 cols]

  const int tid  = threadIdx.x;
  const int lane = tid & 63;
  const int wid  = tid >> 6;       // wave 0..7 = K-slice owner
  const int g    = lane >> 4;      // 16-lane group 0..3
  const int cc   = lane & 15;
  const int kw0  = wid << 7;       // this wave's K-offset (dims)

  const int blk_base = blockIdx.x * RPB;
  int limit = blk_base + RPB; if (limit > N) limit = N;

  // ---- issue tile-0 X loads FIRST (NT, row-pair 512B bursts)
  f32x4 nxt[8];
  #pragma unroll
  for (int j = 0; j < 8; ++j) {
    int r = blk_base + 2 * j + (lane >> 5);
    if (r >= limit) r = limit - 1;
    nxt[j] = __builtin_nontemporal_load(
        (const f32x4*)(X + (size_t)r * DDIM + kw0 + (lane & 31) * 4));
  }

  // ---- B-fragments: 8 KB linear per wave from the compact table (L2-hot)
  short8v bfrag[4][2];
  #pragma unroll
  for (int sp = 0; sp < 4; ++sp)
    #pragma unroll
    for (int h = 0; h < 2; ++h)
      bfrag[sp][h] = *(const short8v*)(
          tbl + ((size_t)(((wid << 2) + sp) * 2 + h) * 64 + lane) * 8);

  // ---- sq: 3 scalar loads (tiny, L2-hot); no LDS phases, no prologue sync
  const float* sqG = (const float*)(tbl + 32768);
  const float sq0   = sqG[cc];
  const float sq1   = sqG[cc + 16];
  const float sqcol = sqG[tid & 31];   // for the reduce phase

  // ---- per-wave LDS addresses (proven swizzle for the X stage)
  char* ldsXb = (char*)ldsX + wid * 4096;
  const int wb0 = ((lane >> 5) << 8) + (lane & 31) * 8;  // row-half*256 + col*8
  int raddr[4];
  #pragma unroll
  for (int sp = 0; sp < 4; ++sp) {
    int a = cc * 256 + (sp * 4 + g) * 16;
    raddr[sp] = a ^ (((a >> 8) & 0xF) << 4);
  }

  // ---- main: 7 tiles of 16 rows, ONE raw barrier per tile
  #pragma unroll
  for (int t = 0; t < TILES; ++t) {
    // stage tile t (bf16, swizzled) into the wave-private buffer
    #pragma unroll
    for (int j = 0; j < 8; ++j) {
      int wb = wb0 + j * 512;
      wb ^= ((wb >> 8) & 0xF) << 4;
      f32x4 v = nxt[j];
      short4v pk;
      pk[0] = f2bf(v[0]); pk[1] = f2bf(v[1]); pk[2] = f2bf(v[2]); pk[3] = f2bf(v[3]);
      *(short4v*)(ldsXb + wb) = pk;
    }
    // issue tile t+1 NT loads; they stay in flight ACROSS the raw barrier
    if (t < TILES - 1) {
      const int rbn = blk_base + (t + 1) * 16;
      #pragma unroll
      for (int j = 0; j < 8; ++j) {
        int r = rbn + 2 * j + (lane >> 5);
        if (r >= limit) r = limit - 1;
        nxt[j] = __builtin_nontemporal_load(
            (const f32x4*)(X + (size_t)r * DDIM + kw0 + (lane & 31) * 4));
      }
    }
    // 4 k-steps: A from LDS, B from registers
    f32x4 acc0 = {0.f, 0.f, 0.f, 0.f};
    f32x4 acc1 = {0.f, 0.f, 0.f, 0.f};
    #pragma unroll
    for (int sp = 0; sp < 4; ++sp) {
      const short8v a = *(const short8v*)(ldsXb + raddr[sp]);
      acc0 = __builtin_amdgcn_mfma_f32_16x16x32_bf16(a, bfrag[sp][0], acc0, 0, 0, 0);
      acc1 = __builtin_amdgcn_mfma_f32_16x16x32_bf16(a, bfrag[sp][1], acc1, 0, 0, 0);
    }
    // partials -> ldsP[t&1], row-XOR col swizzle (writes/reads <=2-way)
    {
      float* Pw = &ldsP[t & 1][wid * 512];
      #pragma unroll
      for (int r = 0; r < 4; ++r) {
        const int row = (g << 2) + r;
        const int m = (row & 7) << 2;
        Pw[row * 32 + (cc ^ m)]        = acc0[r];
        Pw[row * 32 + ((cc + 16) ^ m)] = acc1[r];
      }
    }
    // ONE raw barrier: LDS visible, global loads stay outstanding
    asm volatile("s_waitcnt lgkmcnt(0)" ::: "memory");
    __builtin_amdgcn_s_barrier();
    asm volatile("" ::: "memory");
    // deterministic 8-wave reduce + fused top-2 (thread = (row, col))
    {
      const int row = tid >> 5, col = tid & 31;
      const int m = (row & 7) << 2;
      const float* Pr = &ldsP[t & 1][row * 32 + (col ^ m)];
      float v = 0.f;
      #pragma unroll
      for (int wv = 0; wv < 8; ++wv) v += Pr[wv * 512];
      float s = fmaf(2.f, v, -sqcol);
      float m1 = s, m2 = -INFINITY;
      #pragma unroll
      for (int d = 1; d <= 16; d <<= 1) {
        float o1 = __shfl_xor(m1, d, 64);
        float o2 = __shfl_xor(m2, d, 64);
        m2 = fmaxf(fmaxf(fminf(m1, o1), o2), m2);  // merged top-2
        m1 = fmaxf(m1, o1);
      }
      const int orow = blk_base + t * 16 + row;
      if ((tid & 31) == 0 && orow < limit) out[orow] = m1 - m2;
    }
    // no second barrier: next tile writes ldsP[(t+1)&1] and private ldsX
  }
}

extern "C" void kernel_launch(void* const* d_in, const int* in_sizes, int n_in,
                              void* d_out, int out_size, void* d_ws, size_t ws_size,
                              hipStream_t stream) {
  const float* X = (const float*)d_in[0];
  const float* C = (const float*)d_in[1];
  float* out = (float*)d_out;
  short* tbl = (short*)d_ws;                   // 64 KB frags + 128 B sq
  const int N = in_sizes[0] / DDIM;            // 50000
  const int blocks = (N + RPB - 1) / RPB;      // 511
  hipLaunchKernelGGL(nkm_pre_kernel, dim3(96), dim3(64), 0, stream, C, tbl);
  hipLaunchKernelGGL(nkm_ksplit_kernel, dim3(blocks), dim3(BLK), 0, stream,
                     X, tbl, out, N);
}

// Round 15
// 39.666 us; speedup vs baseline: 1.0390x; 1.0390x over previous
//
#include <hip/hip_runtime.h>
#include <hip/hip_bf16.h>
#include <math.h>

// out[n] = top1(s) - top2(s),  s_c = 2 mu_c.x - ||mu_c||^2
//
// Kernel 1 (96 blocks x 64 thr): compact bf16 B-fragment table (64 KB) in
//   PER-WAVE GATHER ORDER + bf16-consistent ||mu||^2 (128 B) into d_ws.
// Kernel 2 (511 blocks x 512 thr, 98 rows/block, 2 blocks/CU): K-split:
//   wave w owns dims [128w,128w+128); B-frags in 32 VGPR/lane from tbl
//   (8 KB linear per wave, L2-hot); X streamed with PLAIN loads (NT
//   reverted: present in both historical regressions r4/r14 -- evict-first
//   defeats L2 read-combining + clamped-row broadcast) as 512B row-pair
//   bursts into wave-private 4KB XOR-swizzled LDS; 4 k-steps {ds_read_b128
//   + 2 MFMA}; partials -> ldsP[t&1] (row-XOR swizzle); ONE raw barrier per
//   tile (lgkmcnt only -- vmcnt never drained in-loop); 8-wave reduce +
//   fused top-2. No prologue barrier (sq via scalar loads).
// A and B use the same k-slot mapping -> dot invariant to slot permutation.

#define KTOT  32
#define DDIM  1024
#define BLK   512
#define RPB   98
#define TILES 7      // ceil(98/16)

typedef __attribute__((ext_vector_type(8))) short short8v;
typedef __attribute__((ext_vector_type(4))) short short4v;
typedef __attribute__((ext_vector_type(4))) float f32x4;

__device__ __forceinline__ short f2bf(float x) {  // RNE; pairs into v_cvt_pk_bf16_f32
  __hip_bfloat16 h = __float2bfloat16(x);
  return __builtin_bit_cast(short, h);
}
__device__ __forceinline__ float bf2f(short b) {
  return __uint_as_float(((unsigned)(unsigned short)b) << 16);
}

// ---------------- kernel 1: compact frag table (gather order) + sq --------
__global__ __launch_bounds__(64)
void nkm_pre_kernel(const float* __restrict__ Cent, short* __restrict__ tbl) {
  const int b = blockIdx.x, t = threadIdx.x;
  if (b < 64) {
    // item i = ((wid*4+sp)*2+h)*64 + lane  (exactly main-kernel read order)
    const int i    = b * 64 + t;         // 0..4095
    const int lane = i & 63;
    const int sh   = i >> 6;             // (wid*4+sp)*2+h
    const int h    = sh & 1;
    const int sp   = (sh >> 1) & 3;
    const int wid  = sh >> 3;
    const int cc   = lane & 15, g = lane >> 4;
    const int col  = cc + (h << 4);
    const float* cp = Cent + (size_t)col * DDIM + (wid << 7) + sp * 32 + (g << 3);
    f32x4 f0 = *(const f32x4*)cp;
    f32x4 f1 = *(const f32x4*)(cp + 4);
    short8v v;
    v[0] = f2bf(f0[0]); v[1] = f2bf(f0[1]); v[2] = f2bf(f0[2]); v[3] = f2bf(f0[3]);
    v[4] = f2bf(f1[0]); v[5] = f2bf(f1[1]); v[6] = f2bf(f1[2]); v[7] = f2bf(f1[3]);
    *(short8v*)(tbl + (size_t)i * 8) = v;
  } else {
    // ||mu_col||^2 from bf16-ROUNDED values (operand-consistent with MFMA B)
    const int col = b - 64;              // 0..31
    const float* cp = Cent + (size_t)col * DDIM + t * 16;
    float s = 0.f;
    #pragma unroll
    for (int j = 0; j < 4; ++j) {
      f32x4 v = *(const f32x4*)(cp + j * 4);
      #pragma unroll
      for (int e = 0; e < 4; ++e) {
        float bv = bf2f(f2bf(v[e]));
        s = fmaf(bv, bv, s);
      }
    }
    #pragma unroll
    for (int d = 1; d < 64; d <<= 1) s += __shfl_xor(s, d, 64);
    if (t == 0) ((float*)(tbl + 32768))[col] = s;
  }
}

// ---------------- kernel 2: K-split streamer ------------------------------
__global__ __launch_bounds__(BLK, 4)
void nkm_ksplit_kernel(const float* __restrict__ X,
                       const short* __restrict__ tbl,
                       float* __restrict__ out, int N) {
  __shared__ short ldsX[16384];    // 32 KB: 8 waves x 4 KB X-stage (wave-private)
  __shared__ float ldsP[2][4096];  // 2 x 16 KB: [buf][8 waves][16 rows][32 cols]

  const int tid  = threadIdx.x;
  const int lane = tid & 63;
  const int wid  = tid >> 6;       // wave 0..7 = K-slice owner
  const int g    = lane >> 4;      // 16-lane group 0..3
  const int cc   = lane & 15;
  const int kw0  = wid << 7;       // this wave's K-offset (dims)

  const int blk_base = blockIdx.x * RPB;
  int limit = blk_base + RPB; if (limit > N) limit = N;

  // ---- issue tile-0 X loads FIRST (plain loads, row-pair 512B bursts)
  f32x4 nxt[8];
  #pragma unroll
  for (int j = 0; j < 8; ++j) {
    int r = blk_base + 2 * j + (lane >> 5);
    if (r >= limit) r = limit - 1;
    nxt[j] = *(const f32x4*)(X + (size_t)r * DDIM + kw0 + (lane & 31) * 4);
  }

  // ---- B-fragments: 8 KB linear per wave from the compact table (L2-hot)
  short8v bfrag[4][2];
  #pragma unroll
  for (int sp = 0; sp < 4; ++sp)
    #pragma unroll
    for (int h = 0; h < 2; ++h)
      bfrag[sp][h] = *(const short8v*)(
          tbl + ((size_t)(((wid << 2) + sp) * 2 + h) * 64 + lane) * 8);

  // ---- sq: 3 scalar loads (tiny, L2-hot); no LDS phases, no prologue sync
  const float* sqG = (const float*)(tbl + 32768);
  const float sq0   = sqG[cc];
  const float sq1   = sqG[cc + 16];
  const float sqcol = sqG[tid & 31];   // for the reduce phase

  // ---- per-wave LDS addresses (proven swizzle for the X stage)
  char* ldsXb = (char*)ldsX + wid * 4096;
  const int wb0 = ((lane >> 5) << 8) + (lane & 31) * 8;  // row-half*256 + col*8
  int raddr[4];
  #pragma unroll
  for (int sp = 0; sp < 4; ++sp) {
    int a = cc * 256 + (sp * 4 + g) * 16;
    raddr[sp] = a ^ (((a >> 8) & 0xF) << 4);
  }

  // ---- main: 7 tiles of 16 rows, ONE raw barrier per tile
  #pragma unroll
  for (int t = 0; t < TILES; ++t) {
    // stage tile t (bf16, swizzled) into the wave-private buffer
    #pragma unroll
    for (int j = 0; j < 8; ++j) {
      int wb = wb0 + j * 512;
      wb ^= ((wb >> 8) & 0xF) << 4;
      f32x4 v = nxt[j];
      short4v pk;
      pk[0] = f2bf(v[0]); pk[1] = f2bf(v[1]); pk[2] = f2bf(v[2]); pk[3] = f2bf(v[3]);
      *(short4v*)(ldsXb + wb) = pk;
    }
    // issue tile t+1 loads; they stay in flight ACROSS the raw barrier
    if (t < TILES - 1) {
      const int rbn = blk_base + (t + 1) * 16;
      #pragma unroll
      for (int j = 0; j < 8; ++j) {
        int r = rbn + 2 * j + (lane >> 5);
        if (r >= limit) r = limit - 1;
        nxt[j] = *(const f32x4*)(X + (size_t)r * DDIM + kw0 + (lane & 31) * 4);
      }
    }
    // 4 k-steps: A from LDS, B from registers
    f32x4 acc0 = {0.f, 0.f, 0.f, 0.f};
    f32x4 acc1 = {0.f, 0.f, 0.f, 0.f};
    #pragma unroll
    for (int sp = 0; sp < 4; ++sp) {
      const short8v a = *(const short8v*)(ldsXb + raddr[sp]);
      acc0 = __builtin_amdgcn_mfma_f32_16x16x32_bf16(a, bfrag[sp][0], acc0, 0, 0, 0);
      acc1 = __builtin_amdgcn_mfma_f32_16x16x32_bf16(a, bfrag[sp][1], acc1, 0, 0, 0);
    }
    // partials -> ldsP[t&1], row-XOR col swizzle (writes/reads <=2-way)
    {
      float* Pw = &ldsP[t & 1][wid * 512];
      #pragma unroll
      for (int r = 0; r < 4; ++r) {
        const int row = (g << 2) + r;
        const int m = (row & 7) << 2;
        Pw[row * 32 + (cc ^ m)]        = acc0[r];
        Pw[row * 32 + ((cc + 16) ^ m)] = acc1[r];
      }
    }
    // ONE raw barrier: LDS visible, global loads stay outstanding
    asm volatile("s_waitcnt lgkmcnt(0)" ::: "memory");
    __builtin_amdgcn_s_barrier();
    asm volatile("" ::: "memory");
    // deterministic 8-wave reduce + fused top-2 (thread = (row, col))
    {
      const int row = tid >> 5, col = tid & 31;
      const int m = (row & 7) << 2;
      const float* Pr = &ldsP[t & 1][row * 32 + (col ^ m)];
      float v = 0.f;
      #pragma unroll
      for (int wv = 0; wv < 8; ++wv) v += Pr[wv * 512];
      float s = fmaf(2.f, v, -sqcol);
      float m1 = s, m2 = -INFINITY;
      #pragma unroll
      for (int d = 1; d <= 16; d <<= 1) {
        float o1 = __shfl_xor(m1, d, 64);
        float o2 = __shfl_xor(m2, d, 64);
        m2 = fmaxf(fmaxf(fminf(m1, o1), o2), m2);  // merged top-2
        m1 = fmaxf(m1, o1);
      }
      const int orow = blk_base + t * 16 + row;
      if ((tid & 31) == 0 && orow < limit) out[orow] = m1 - m2;
    }
    // no second barrier: next tile writes ldsP[(t+1)&1] and private ldsX
  }
}

extern "C" void kernel_launch(void* const* d_in, const int* in_sizes, int n_in,
                              void* d_out, int out_size, void* d_ws, size_t ws_size,
                              hipStream_t stream) {
  const float* X = (const float*)d_in[0];
  const float* C = (const float*)d_in[1];
  float* out = (float*)d_out;
  short* tbl = (short*)d_ws;                   // 64 KB frags + 128 B sq
  const int N = in_sizes[0] / DDIM;            // 50000
  const int blocks = (N + RPB - 1) / RPB;      // 511
  hipLaunchKernelGGL(nkm_pre_kernel, dim3(96), dim3(64), 0, stream, C, tbl);
  hipLaunchKernelGGL(nkm_ksplit_kernel, dim3(blocks), dim3(BLK), 0, stream,
                     X, tbl, out, N);
}

// Round 16
// 38.056 us; speedup vs baseline: 1.0830x; 1.0423x over previous
//
#include <hip/hip_runtime.h>
#include <hip/hip_bf16.h>
#include <math.h>

// out[n] = top1(s) - top2(s),  s_c = 2 mu_c.x - ||mu_c||^2
//
// K-SPLIT kernel (511 blocks x 512 thr, 98 rows/block, 2 blocks/CU) --
// round-13 structure (best, 38.25us) with its last vmcnt drain removed:
//  - wave w owns K-dims [128w, 128w+128); B-frags (32 cols x 128 dims bf16)
//    entirely in 32 VGPRs/lane, gathered in-kernel from fp32 Cent (L2/L3-hot)
//  - per 16-row tile: X staged as 512B-contiguous row-pair bursts into a
//    wave-private 4 KB XOR-swizzled LDS buffer; 4 k-steps {ds_read_b128 A +
//    2 MFMA}; partials -> double-buffered ldsP[t&1] (row-XOR col swizzle);
//    ONE raw barrier per tile (s_waitcnt lgkmcnt(0); s_barrier) -- vmcnt is
//    NEVER drained, next-tile X loads stay in flight across barriers
//  - THIS ROUND: the prologue barrier is also raw lgkm-only (round 13 used
//    __syncthreads -> vmcnt(0) drain of tile-0 X + all bfrag gathers at t=0
//    for all 511 blocks; the only cross-wave data there is LDS sqP)
//  - deterministic 8-wave reduce + fused top-2 after the barrier
// A and B use the same k-slot mapping -> dot invariant to slot permutation.

#define KTOT  32
#define DDIM  1024
#define BLK   512
#define RPB   98
#define TILES 7      // ceil(98/16)

typedef __attribute__((ext_vector_type(8))) short short8v;
typedef __attribute__((ext_vector_type(4))) short short4v;
typedef __attribute__((ext_vector_type(4))) float f32x4;

__device__ __forceinline__ short f2bf(float x) {  // RNE; pairs into v_cvt_pk_bf16_f32
  __hip_bfloat16 h = __float2bfloat16(x);
  return __builtin_bit_cast(short, h);
}
__device__ __forceinline__ float bf2f(short b) {
  return __uint_as_float(((unsigned)(unsigned short)b) << 16);
}

__global__ __launch_bounds__(BLK, 4)
void nkm_ksplit_kernel(const float* __restrict__ X,
                       const float* __restrict__ Cent,
                       float* __restrict__ out, int N) {
  __shared__ short ldsX[16384];    // 32 KB: 8 waves x 4 KB X-stage (wave-private)
  __shared__ float ldsP[2][4096];  // 2 x 16 KB: [buf][8 waves][16 rows][32 cols]
  __shared__ float sqP[256];       // 1 KB : [8 waves][32 cols]
  __shared__ float sqArr[KTOT];    // 128 B

  const int tid  = threadIdx.x;
  const int lane = tid & 63;
  const int wid  = tid >> 6;       // wave 0..7 = K-slice owner
  const int g    = lane >> 4;      // 16-lane group 0..3
  const int cc   = lane & 15;
  const int kw0  = wid << 7;       // this wave's K-offset (dims)

  const int blk_base = blockIdx.x * RPB;
  int limit = blk_base + RPB; if (limit > N) limit = N;

  // ---- issue tile-0 X loads FIRST (row-pair 512B bursts, proven pattern)
  f32x4 nxt[8];
  #pragma unroll
  for (int j = 0; j < 8; ++j) {
    int r = blk_base + 2 * j + (lane >> 5);
    if (r >= limit) r = limit - 1;
    nxt[j] = *(const f32x4*)(X + (size_t)r * DDIM + kw0 + (lane & 31) * 4);
  }

  // ---- gather B-fragments into registers (16 KB fp32 per wave, L2/L3-hot)
  short8v bfrag[4][2];
  float psq0 = 0.f, psq1 = 0.f;
  #pragma unroll
  for (int sp = 0; sp < 4; ++sp) {
    #pragma unroll
    for (int h = 0; h < 2; ++h) {
      const int col = cc + (h << 4);
      const float* cp = Cent + (size_t)col * DDIM + kw0 + sp * 32 + (g << 3);
      f32x4 f0 = *(const f32x4*)cp;
      f32x4 f1 = *(const f32x4*)(cp + 4);
      short8v v;
      v[0] = f2bf(f0[0]); v[1] = f2bf(f0[1]); v[2] = f2bf(f0[2]); v[3] = f2bf(f0[3]);
      v[4] = f2bf(f1[0]); v[5] = f2bf(f1[1]); v[6] = f2bf(f1[2]); v[7] = f2bf(f1[3]);
      bfrag[sp][h] = v;
      float s = 0.f;
      #pragma unroll
      for (int e = 0; e < 8; ++e) { float bv = bf2f(v[e]); s = fmaf(bv, bv, s); }
      if (h == 0) psq0 += s; else psq1 += s;
    }
  }
  psq0 += __shfl_xor(psq0, 16, 64);  psq0 += __shfl_xor(psq0, 32, 64);
  psq1 += __shfl_xor(psq1, 16, 64);  psq1 += __shfl_xor(psq1, 32, 64);
  if (g == 0 && (lane >> 5) == 0) {  // lanes 0..15
    sqP[wid * 32 + cc]      = psq0;
    sqP[wid * 32 + 16 + cc] = psq1;
  }
  // raw prologue barrier: only LDS (sqP) needs cross-wave visibility;
  // tile-0 X loads and any straggling gathers stay in flight (no vmcnt drain)
  asm volatile("s_waitcnt lgkmcnt(0)" ::: "memory");
  __builtin_amdgcn_s_barrier();
  asm volatile("" ::: "memory");
  if (tid < KTOT) {
    float s = 0.f;
    #pragma unroll
    for (int wv = 0; wv < 8; ++wv) s += sqP[wv * 32 + tid];
    sqArr[tid] = s;   // visible to all after tile-0's in-loop barrier
  }

  // ---- per-wave LDS addresses (proven swizzle for the X stage)
  char* ldsXb = (char*)ldsX + wid * 4096;
  const int wb0 = ((lane >> 5) << 8) + (lane & 31) * 8;  // row-half*256 + col*8
  int raddr[4];
  #pragma unroll
  for (int sp = 0; sp < 4; ++sp) {
    int a = cc * 256 + (sp * 4 + g) * 16;
    raddr[sp] = a ^ (((a >> 8) & 0xF) << 4);
  }

  // ---- main: 7 tiles of 16 rows, ONE raw barrier per tile
  #pragma unroll
  for (int t = 0; t < TILES; ++t) {
    // stage tile t (bf16, swizzled) into the wave-private buffer
    #pragma unroll
    for (int j = 0; j < 8; ++j) {
      int wb = wb0 + j * 512;
      wb ^= ((wb >> 8) & 0xF) << 4;
      f32x4 v = nxt[j];
      short4v pk;
      pk[0] = f2bf(v[0]); pk[1] = f2bf(v[1]); pk[2] = f2bf(v[2]); pk[3] = f2bf(v[3]);
      *(short4v*)(ldsXb + wb) = pk;
    }
    // issue tile t+1 loads; they stay in flight ACROSS the raw barrier
    if (t < TILES - 1) {
      const int rbn = blk_base + (t + 1) * 16;
      #pragma unroll
      for (int j = 0; j < 8; ++j) {
        int r = rbn + 2 * j + (lane >> 5);
        if (r >= limit) r = limit - 1;
        nxt[j] = *(const f32x4*)(X + (size_t)r * DDIM + kw0 + (lane & 31) * 4);
      }
    }
    // 4 k-steps: A from LDS, B from registers
    f32x4 acc0 = {0.f, 0.f, 0.f, 0.f};
    f32x4 acc1 = {0.f, 0.f, 0.f, 0.f};
    #pragma unroll
    for (int sp = 0; sp < 4; ++sp) {
      const short8v a = *(const short8v*)(ldsXb + raddr[sp]);
      acc0 = __builtin_amdgcn_mfma_f32_16x16x32_bf16(a, bfrag[sp][0], acc0, 0, 0, 0);
      acc1 = __builtin_amdgcn_mfma_f32_16x16x32_bf16(a, bfrag[sp][1], acc1, 0, 0, 0);
    }
    // partials -> ldsP[t&1], row-XOR col swizzle (writes/reads <=2-way)
    {
      float* Pw = &ldsP[t & 1][wid * 512];
      #pragma unroll
      for (int r = 0; r < 4; ++r) {
        const int row = (g << 2) + r;
        const int m = (row & 7) << 2;
        Pw[row * 32 + (cc ^ m)]        = acc0[r];
        Pw[row * 32 + ((cc + 16) ^ m)] = acc1[r];
      }
    }
    // ONE raw barrier: LDS visible, global loads stay outstanding
    asm volatile("s_waitcnt lgkmcnt(0)" ::: "memory");
    __builtin_amdgcn_s_barrier();
    asm volatile("" ::: "memory");
    // deterministic 8-wave reduce + fused top-2 (thread = (row, col))
    {
      const int row = tid >> 5, col = tid & 31;
      const int m = (row & 7) << 2;
      const float* Pr = &ldsP[t & 1][row * 32 + (col ^ m)];
      float v = 0.f;
      #pragma unroll
      for (int wv = 0; wv < 8; ++wv) v += Pr[wv * 512];
      float s = fmaf(2.f, v, -sqArr[col]);
      float m1 = s, m2 = -INFINITY;
      #pragma unroll
      for (int d = 1; d <= 16; d <<= 1) {
        float o1 = __shfl_xor(m1, d, 64);
        float o2 = __shfl_xor(m2, d, 64);
        m2 = fmaxf(fmaxf(fminf(m1, o1), o2), m2);  // merged top-2
        m1 = fmaxf(m1, o1);
      }
      const int orow = blk_base + t * 16 + row;
      if ((tid & 31) == 0 && orow < limit) out[orow] = m1 - m2;
    }
    // no second barrier: next tile writes ldsP[(t+1)&1] and private ldsX
  }
}

extern "C" void kernel_launch(void* const* d_in, const int* in_sizes, int n_in,
                              void* d_out, int out_size, void* d_ws, size_t ws_size,
                              hipStream_t stream) {
  const float* X = (const float*)d_in[0];
  const float* C = (const float*)d_in[1];
  float* out = (float*)d_out;
  const int N = in_sizes[0] / DDIM;            // 50000
  const int blocks = (N + RPB - 1) / RPB;      // 511
  hipLaunchKernelGGL(nkm_ksplit_kernel, dim3(blocks), dim3(BLK), 0, stream,
                     X, C, out, N);
}